// Round 2
// baseline (39369.315 us; speedup 1.0000x reference)
//
#include <hip/hip_runtime.h>
#include <hip/hip_bf16.h>

// Problem dims
#define DP   256
#define DD   320
#define KK   10
#define CC   10
#define DOUT 64
#define SEQn 512
#define BB   32
#define NTH  640   // 10 waves

// workspace layout (floats): only the transposed Na_w
#define NAT_OFF 0   // [30][3200]

__global__ void prep_kernel(const float* __restrict__ NaW,
                            float* __restrict__ ws) {
    int idx = blockIdx.x * blockDim.x + threadIdx.x;
    int stride = gridDim.x * blockDim.x;
    float* naT = ws + NAT_OFF;
    for (int i = idx; i < 96000; i += stride) {
        int o = i / 3200, r = i - o * 3200;
        naT[i] = NaW[r * 30 + o];
    }
}

__global__ __launch_bounds__(NTH) void recur_kernel(
    const int* __restrict__ sentence, const int* __restrict__ speaker,
    const float* __restrict__ LutP, const float* __restrict__ LutS,
    const float* __restrict__ NaB,
    const float* __restrict__ NuW, const float* __restrict__ NuB,
    const float* __restrict__ NoW, const float* __restrict__ NoB,
    const float* __restrict__ FuW, const float* __restrict__ FuB,
    const float* __restrict__ FoW, const float* __restrict__ FoB,
    const float* __restrict__ ws, const int* __restrict__ Tptr,
    float* __restrict__ out)
{
    const int b = blockIdx.x;
    const int tid = threadIdx.x;
    const float* naT = ws + NAT_OFF;

    __shared__ float xS[3200];      // S flat: xS[d*10+k]
    __shared__ float col[DD];       // staged column (C_t)
    __shared__ float part[2560];    // matvec partials
    __shared__ float alpha[SEQn];
    __shared__ float idt[DP];
    __shared__ float identsh[DP];
    __shared__ float foNo[DOUT];
    __shared__ float o_prev[DOUT];
    __shared__ float mu[CC];
    __shared__ float sgg[CC];
    __shared__ float gg[CC];
    __shared__ float aout[32];
    __shared__ float nub[DD];
    __shared__ float nab[32];
    __shared__ int   sent[SEQn];

    // ---------------- prologue ----------------
    for (int i = tid; i < SEQn; i += NTH) sent[i] = sentence[b * SEQn + i];
    const int spk = speaker[b];
    for (int d = tid; d < DP; d += NTH) identsh[d] = LutS[spk * DP + d];
    for (int o = tid; o < DD; o += NTH) nub[o] = NuB[o];
    if (tid < 30) nab[tid] = NaB[tid];
    if (tid < CC) mu[tid] = 0.f;
    if (tid < DOUT) o_prev[tid] = 0.f;
    __syncthreads();

    // idt = tanh(ident @ Fu_w + Fu_b)
    if (tid < DP) {
        float acc = FuB[tid];
        for (int j = 0; j < DP; ++j) acc += identsh[j] * FuW[j * DP + tid];
        idt[tid] = tanhf(acc);
    }
    // fo = ident @ Fo_w + Fo_b  (stored temporarily in xS)
    for (int r = tid; r < 3200; r += NTH) {
        float acc = FoB[r];
        for (int j = 0; j < DP; ++j) acc += identsh[j] * FoW[j * 3200 + r];
        xS[r] = acc;
    }
    __syncthreads();
    // foNo = fo @ No_w + No_b
    {
        int g = tid / 64, o = tid & 63;   // 10 groups x 64
        float acc = 0.f;
        for (int r = g * 320; r < g * 320 + 320; ++r) acc += xS[r] * NoW[r * 64 + o];
        part[g * 64 + o] = acc;
    }
    __syncthreads();
    if (tid < DOUT) {
        float acc = NoB[tid];
        #pragma unroll
        for (int g = 0; g < 10; ++g) acc += part[g * 64 + tid];
        foNo[tid] = acc;
    }
    __syncthreads();
    // init xS = S0 flat: every tap column = [ident ; 0]
    for (int i = tid; i < 3200; i += NTH) {
        int d = i / KK;
        xS[i] = (d < DP) ? identsh[d] : 0.f;
    }
    __syncthreads();

    const int T = Tptr[0];
    const float4* nu4 = (const float4*)NuW;
    const float4* no4 = (const float4*)NoW;

    for (int t = 0; t < T; ++t) {
        // ---- A: aout[0..29] = S_{t-1}.flat @ Na_w + Na_b  (naT transposed) ----
        {
            int g = tid >> 4, l = tid & 15;
            if (g < 30) {
                float acc = 0.f;
                const float* wrow = naT + g * 3200;
                #pragma unroll 5
                for (int i = 0; i < 50; ++i) {
                    int r = 4 * l + 64 * i;
                    float4 xv = *(const float4*)&xS[r];
                    float4 wv = *(const float4*)&wrow[r];
                    acc += xv.x * wv.x + xv.y * wv.y + xv.z * wv.z + xv.w * wv.w;
                }
                #pragma unroll
                for (int off = 8; off; off >>= 1) acc += __shfl_xor(acc, off, 16);
                if (l == 0) aout[g] = acc + nab[g];
            }
        }
        __syncthreads();
        // ---- B: mu += 0.05*exp(k); sig = exp(b); g = softmax(y) ----
        if (tid < CC) {
            float kk = aout[tid], bb2 = aout[10 + tid], yy = aout[20 + tid];
            mu[tid] += 0.05f * expf(kk);
            sgg[tid] = expf(bb2);
            float m = -1e30f;
            for (int j = 0; j < CC; ++j) m = fmaxf(m, aout[20 + j]);
            float s = 0.f;
            for (int j = 0; j < CC; ++j) s += expf(aout[20 + j] - m);
            gg[tid] = expf(yy - m) / s;
        }
        __syncthreads();
        // ---- C1: alpha[s] = COEF * sum_c g_c * exp(-0.5*sig_c*(mu_c - (s+1))^2) ----
        if (tid < SEQn) {
            float J = (float)(tid + 1);
            float a = 0.f;
            #pragma unroll
            for (int c = 0; c < CC; ++c) {
                float dmu = mu[c] - J;
                a += gg[c] * __expf(-0.5f * sgg[c] * dmu * dmu);
            }
            alpha[tid] = a * 0.3989422917366028f;
        }
        __syncthreads();
        // ---- C2: col = C_t = [c_t + idt ; o_prev/30] ----
        if (tid < DP) {
            float acc = 0.f;
            for (int s = 0; s < SEQn; ++s)
                acc += alpha[s] * LutP[sent[s] * DP + tid];
            col[tid] = acc + idt[tid];
        } else if (tid < DD) {
            col[tid] = o_prev[tid - DP] * (1.0f / 30.0f);
        }
        __syncthreads();
        // ---- D: shift register, insert C_t at tap 0  (xS = Sp) ----
        if (tid < DD) {
            int base = tid * KK;
            float v[9];
            #pragma unroll
            for (int k = 0; k < 9; ++k) v[k] = xS[base + k];
            #pragma unroll
            for (int k = 0; k < 9; ++k) xS[base + k + 1] = v[k];
            xS[base] = col[tid];
        }
        __syncthreads();
        // ---- E: u = Sp.flat @ Nu_w + Nu_b  (80 oquads x 8 r-groups) ----
        {
            int oq = tid % 80, g = tid / 80;
            float4 acc = make_float4(0.f, 0.f, 0.f, 0.f);
            int r0 = g * 400;
            for (int r = r0; r < r0 + 400; ++r) {
                float xv = xS[r];
                float4 w = nu4[r * 80 + oq];
                acc.x += xv * w.x; acc.y += xv * w.y;
                acc.z += xv * w.z; acc.w += xv * w.w;
            }
            int o = oq * 4;
            part[g * 320 + o]     = acc.x;
            part[g * 320 + o + 1] = acc.y;
            part[g * 320 + o + 2] = acc.z;
            part[g * 320 + o + 3] = acc.w;
        }
        __syncthreads();
        if (tid < DD) {
            float u = nub[tid];
            #pragma unroll
            for (int g = 0; g < 8; ++g) u += part[g * 320 + tid];
            xS[tid * KK] = u;   // front column := u  => xS = S_t
        }
        __syncthreads();
        // ---- G: o_t = S_t.flat @ No_w + foNo  (16 oquads x 40 r-groups) ----
        {
            int oq = tid & 15, g = tid >> 4;
            float4 acc = make_float4(0.f, 0.f, 0.f, 0.f);
            int r0 = g * 80;
            for (int r = r0; r < r0 + 80; ++r) {
                float xv = xS[r];
                float4 w = no4[r * 16 + oq];
                acc.x += xv * w.x; acc.y += xv * w.y;
                acc.z += xv * w.z; acc.w += xv * w.w;
            }
            int o = oq * 4;
            part[g * 64 + o]     = acc.x;
            part[g * 64 + o + 1] = acc.y;
            part[g * 64 + o + 2] = acc.z;
            part[g * 64 + o + 3] = acc.w;
        }
        __syncthreads();
        if (tid < DOUT) {
            float ov = foNo[tid];
            #pragma unroll
            for (int g = 0; g < 40; ++g) ov += part[g * 64 + tid];
            o_prev[tid] = ov;
            out[((size_t)t * BB + b) * DOUT + tid] = ov;
        }
        __syncthreads();
    }
}

extern "C" void kernel_launch(void* const* d_in, const int* in_sizes, int n_in,
                              void* d_out, int out_size, void* d_ws, size_t ws_size,
                              hipStream_t stream) {
    const int*   sentence = (const int*)d_in[0];
    const int*   speaker  = (const int*)d_in[1];
    const float* LutP = (const float*)d_in[2];
    const float* LutS = (const float*)d_in[3];
    const float* NaW  = (const float*)d_in[4];
    const float* NaB  = (const float*)d_in[5];
    const float* NuW  = (const float*)d_in[6];
    const float* NuB  = (const float*)d_in[7];
    const float* NoW  = (const float*)d_in[8];
    const float* NoB  = (const float*)d_in[9];
    const float* FuW  = (const float*)d_in[10];
    const float* FuB  = (const float*)d_in[11];
    const float* FoW  = (const float*)d_in[12];
    const float* FoB  = (const float*)d_in[13];
    const int*   Tptr = (const int*)d_in[14];
    float* ws   = (float*)d_ws;
    float* outp = (float*)d_out;

    hipLaunchKernelGGL(prep_kernel, dim3(256), dim3(256), 0, stream, NaW, ws);
    hipLaunchKernelGGL(recur_kernel, dim3(BB), dim3(NTH), 0, stream,
                       sentence, speaker, LutP, LutS, NaB,
                       NuW, NuB, NoW, NoB, FuW, FuB, FoW, FoB,
                       ws, Tptr, outp);
}

// Round 3
// 16418.236 us; speedup vs baseline: 2.3979x; 2.3979x over previous
//
#include <hip/hip_runtime.h>

// Problem dims
#define DP   256
#define DD   320
#define KK   10
#define CC   10
#define DOUT 64
#define SEQn 512
#define BB   32
#define SI   100
#define NPEER 8
#define RPP  400     // weight rows per peer (3200/8)
#define NTH  640     // 10 waves

// ws layout (4-byte units)
#define CTR_WORDS (BB*32)
#define ABUF_OFF  (CTR_WORDS)
#define ABUF_SZ   (BB*NPEER*32)
#define UBUF_OFF  (ABUF_OFF + ABUF_SZ)
#define UBUF_SZ   (BB*NPEER*DD)
#define OBUF_OFF  (UBUF_OFF + UBUF_SZ)

__global__ void prep_kernel(int* ctr) {
    int i = blockIdx.x * blockDim.x + threadIdx.x;
    if (i < CTR_WORDS) ctr[i] = 0;
}

// 8-peer barrier: monotonic counter, device-scope atomics, sense-free.
__device__ __forceinline__ void gbar(int* c, int target) {
    __syncthreads();
    if (threadIdx.x == 0) {
        __threadfence();
        atomicAdd(c, 1);
        while (__hip_atomic_load(c, __ATOMIC_ACQUIRE, __HIP_MEMORY_SCOPE_AGENT) < target)
            __builtin_amdgcn_s_sleep(2);
        __threadfence();
    }
    __syncthreads();
}

__global__ __launch_bounds__(NTH) void recur_kernel(
    const int* __restrict__ sentence, const int* __restrict__ speaker,
    const float* __restrict__ LutP, const float* __restrict__ LutS,
    const float* __restrict__ NaW,  const float* __restrict__ NaB,
    const float* __restrict__ NuW,  const float* __restrict__ NuB,
    const float* __restrict__ NoW,  const float* __restrict__ NoB,
    const float* __restrict__ FuW,  const float* __restrict__ FuB,
    const float* __restrict__ FoW,  const float* __restrict__ FoB,
    float* __restrict__ ws, const int* __restrict__ Tptr,
    float* __restrict__ out)
{
    const int blk = blockIdx.x;
    const int b = blk >> 3;      // batch group
    const int s = blk & 7;       // peer slice (== XCD under round-robin dispatch)
    const int tid = threadIdx.x;
    int* ctr = (int*)ws + b * 32;
    float* abuf = ws + ABUF_OFF;   // [BB][8][32]
    float* ubuf = ws + UBUF_OFF;   // [BB][8][320]
    float* obuf = ws + OBUF_OFF;   // [BB][8][64]

    __shared__ float xS[3200];     // full state copy, xS[d*10+k]
    __shared__ float part[2560];   // matvec partials (reused A/E/G/foNo)
    __shared__ float alpha[SEQn];
    __shared__ float fos[RPP];
    __shared__ float hpart[640];
    __shared__ float col[DD];
    __shared__ float idt[DP];
    __shared__ float identsh[DP];
    __shared__ float nub[DD];
    __shared__ float hist[128];
    __shared__ float aout[32];
    __shared__ float nab[32];
    __shared__ float foNo[DOUT];
    __shared__ float o_prev[DOUT];
    __shared__ float mu[CC], sgg[CC], gg[CC];
    __shared__ int   sent[SEQn];

    const int rbase0 = s * RPP;

    // ---------------- prologue ----------------
    for (int i = tid; i < SEQn; i += NTH) sent[i] = sentence[b * SEQn + i];
    {
        const int spk = speaker[b];
        for (int d = tid; d < DP; d += NTH) identsh[d] = LutS[spk * DP + d];
    }
    for (int o = tid; o < DD; o += NTH) nub[o] = NuB[o];
    if (tid < 32) nab[tid] = (tid < 30) ? NaB[tid] : 0.f;
    if (tid < CC) mu[tid] = 0.f;
    __syncthreads();
    // idt = tanh(ident @ Fu_w + Fu_b)  (redundant per peer)
    if (tid < DP) {
        float acc = FuB[tid];
        for (int j = 0; j < DP; ++j) acc += identsh[j] * FuW[j * DP + tid];
        idt[tid] = tanhf(acc);
    }
    // fo rows for this slice
    if (tid < RPP) {
        int r = rbase0 + tid;
        float acc = FoB[r];
        for (int j = 0; j < DP; ++j) acc += identsh[j] * FoW[j * 3200 + r];
        fos[tid] = acc;
    }
    __syncthreads();
    // partial foNo over this slice's rows
    {
        int o = tid & 63, rg = tid >> 6;  // 10 groups x 40 rows
        float acc = 0.f;
        for (int i = 0; i < 40; ++i) {
            int lr = rg * 40 + i;
            acc += fos[lr] * NoW[(rbase0 + lr) * 64 + o];
        }
        part[rg * 64 + o] = acc;
    }
    __syncthreads();
    if (tid < DOUT) {
        float v = 0.f;
        for (int rg = 0; rg < 10; ++rg) v += part[rg * 64 + tid];
        ubuf[(b * NPEER + s) * DD + tid] = v;   // temp slot for foNo exchange
    }
    // S0: every tap = [ident ; 0]
    for (int i = tid; i < 3200; i += NTH) {
        int d = i / KK;
        xS[i] = (d < DP) ? identsh[d] : 0.f;
    }
    if (tid < DOUT) obuf[(b * NPEER + s) * DOUT + tid] = 0.f;  // o_0 = 0
    __syncthreads();
    // A-slice on S0
    {
        int o = tid & 31, rg = tid >> 5;   // 20 groups x 20 rows
        float acc = 0.f;
        if (o < 30) {
            int rb = rbase0 + rg * 20;
            for (int i = 0; i < 20; ++i) acc += xS[rb + i] * NaW[(rb + i) * 30 + o];
        }
        part[rg * 32 + o] = acc;
    }
    __syncthreads();
    if (tid < 32) {
        float v = 0.f;
        if (tid < 30)
            for (int rg = 0; rg < 20; ++rg) v += part[rg * 32 + tid];
        abuf[(b * NPEER + s) * 32 + tid] = v;
    }
    gbar(ctr, 8 * 1);
    if (tid < DOUT) {
        float v = NoB[tid];
        for (int p = 0; p < NPEER; ++p) v += ubuf[(b * NPEER + p) * DD + tid];
        foNo[tid] = v;
    }
    __syncthreads();

    const int T = Tptr[0];

    for (int t = 0; t < T; ++t) {
        gbar(ctr, 8 * (2 + 2 * t));
        // assemble aout and o_prev from peer partials (fixed order -> bit-identical)
        if (tid < 32) {
            float v = nab[tid];
            for (int p = 0; p < NPEER; ++p) v += abuf[(b * NPEER + p) * 32 + tid];
            aout[tid] = v;
        } else if (tid >= 64 && tid < 128) {
            int o = tid - 64;
            float v = (t > 0) ? foNo[o] : 0.f;
            for (int p = 0; p < NPEER; ++p) v += obuf[(b * NPEER + p) * DOUT + o];
            o_prev[o] = v;
        }
        __syncthreads();
        if (s == 0 && t > 0 && tid < DOUT)
            out[((size_t)(t - 1) * BB + b) * DOUT + tid] = o_prev[tid];
        // B: attention state update (redundant, identical across peers)
        if (tid < CC) {
            mu[tid] += 0.05f * expf(aout[tid]);
            sgg[tid] = expf(aout[10 + tid]);
            float m = -1e30f;
            for (int j = 0; j < CC; ++j) m = fmaxf(m, aout[20 + j]);
            float ssum = 0.f;
            for (int j = 0; j < CC; ++j) ssum += expf(aout[20 + j] - m);
            gg[tid] = expf(aout[20 + tid] - m) / ssum;
        }
        __syncthreads();
        // C1: alpha
        if (tid < SEQn) {
            float J = (float)(tid + 1);
            float a = 0.f;
            #pragma unroll
            for (int c = 0; c < CC; ++c) { float dm = mu[c] - J; a += gg[c] * __expf(-0.5f * sgg[c] * dm * dm); }
            alpha[tid] = a * 0.3989422917366028f;
        }
        __syncthreads();
        // hist: vocabulary-factored attention (c_t = hist @ LutP)
        {
            int v = tid & 127, c = tid >> 7;    // 5 chunks x 128
            float h = 0.f;
            if (v < SI) {
                int i0 = c * 103, i1 = i0 + 103; if (i1 > SEQn) i1 = SEQn;
                for (int i = i0; i < i1; ++i) h += (sent[i] == v) ? alpha[i] : 0.f;
            }
            hpart[c * 128 + v] = h;
        }
        __syncthreads();
        if (tid < SI) {
            float h = 0.f;
            #pragma unroll
            for (int c = 0; c < 5; ++c) h += hpart[c * 128 + tid];
            hist[tid] = h;
        }
        __syncthreads();
        // C2: col = [hist@LutP + idt ; o_prev/30]
        if (tid < DP) {
            float acc = 0.f;
            for (int v = 0; v < SI; v += 10) {
                float w[10];
                #pragma unroll
                for (int j = 0; j < 10; ++j) w[j] = LutP[(v + j) * DP + tid];
                #pragma unroll
                for (int j = 0; j < 10; ++j) acc += hist[v + j] * w[j];
            }
            col[tid] = acc + idt[tid];
        } else if (tid < DD) {
            col[tid] = o_prev[tid - DP] * (1.0f / 30.0f);
        }
        __syncthreads();
        // D: shift register, insert C_t at tap 0
        if (tid < DD) {
            int base = tid * KK;
            float v[9];
            #pragma unroll
            for (int k = 0; k < 9; ++k) v[k] = xS[base + k];
            #pragma unroll
            for (int k = 0; k < 9; ++k) xS[base + k + 1] = v[k];
            xS[base] = col[tid];
        }
        __syncthreads();
        // E-slice: partial u over rows [s*400,(s+1)*400), batched loads for ILP
        {
            int oq = tid % 80, g = tid / 80;   // 8 groups x 50 rows
            const float4* nu4 = (const float4*)NuW;
            int rb = rbase0 + g * 50;
            float4 acc = make_float4(0.f, 0.f, 0.f, 0.f);
            for (int i = 0; i < 50; i += 10) {
                float4 w[10]; float x[10];
                #pragma unroll
                for (int j = 0; j < 10; ++j) w[j] = nu4[(rb + i + j) * 80 + oq];
                #pragma unroll
                for (int j = 0; j < 10; ++j) x[j] = xS[rb + i + j];
                #pragma unroll
                for (int j = 0; j < 10; ++j) {
                    acc.x += x[j] * w[j].x; acc.y += x[j] * w[j].y;
                    acc.z += x[j] * w[j].z; acc.w += x[j] * w[j].w;
                }
            }
            int o4 = oq * 4;
            part[g * 320 + o4]     = acc.x;
            part[g * 320 + o4 + 1] = acc.y;
            part[g * 320 + o4 + 2] = acc.z;
            part[g * 320 + o4 + 3] = acc.w;
        }
        __syncthreads();
        if (tid < DD) {
            float v = 0.f;
            #pragma unroll
            for (int g = 0; g < 8; ++g) v += part[g * 320 + tid];
            ubuf[(b * NPEER + s) * DD + tid] = v;
        }
        gbar(ctr, 8 * (3 + 2 * t));
        // u assemble + insert into tap 0
        if (tid < DD) {
            float v = nub[tid];
            for (int p = 0; p < NPEER; ++p) v += ubuf[(b * NPEER + p) * DD + tid];
            xS[tid * KK] = v;
        }
        __syncthreads();
        // G-slice: partial o over this slice's rows
        {
            int oq = tid & 15, g = tid >> 4;   // 40 groups x 10 rows
            const float4* no4 = (const float4*)NoW;
            int rb = rbase0 + g * 10;
            float4 acc = make_float4(0.f, 0.f, 0.f, 0.f);
            float4 w[10]; float x[10];
            #pragma unroll
            for (int j = 0; j < 10; ++j) w[j] = no4[(rb + j) * 16 + oq];
            #pragma unroll
            for (int j = 0; j < 10; ++j) x[j] = xS[rb + j];
            #pragma unroll
            for (int j = 0; j < 10; ++j) {
                acc.x += x[j] * w[j].x; acc.y += x[j] * w[j].y;
                acc.z += x[j] * w[j].z; acc.w += x[j] * w[j].w;
            }
            int o4 = oq * 4;
            part[g * 64 + o4]     = acc.x;
            part[g * 64 + o4 + 1] = acc.y;
            part[g * 64 + o4 + 2] = acc.z;
            part[g * 64 + o4 + 3] = acc.w;
        }
        __syncthreads();
        if (tid < DOUT) {
            float v = 0.f;
            #pragma unroll
            for (int g = 0; g < 40; ++g) v += part[g * 64 + tid];
            obuf[(b * NPEER + s) * DOUT + tid] = v;
        }
        __syncthreads();   // before reusing part[] in A
        // A-slice on S_t (for next step)
        {
            int o = tid & 31, rg = tid >> 5;   // 20 groups x 20 rows
            float acc = 0.f;
            if (o < 30) {
                int rb = rbase0 + rg * 20;
                for (int i = 0; i < 20; i += 10) {
                    float w[10], x[10];
                    #pragma unroll
                    for (int j = 0; j < 10; ++j) w[j] = NaW[(rb + i + j) * 30 + o];
                    #pragma unroll
                    for (int j = 0; j < 10; ++j) x[j] = xS[rb + i + j];
                    #pragma unroll
                    for (int j = 0; j < 10; ++j) acc += x[j] * w[j];
                }
            }
            part[rg * 32 + o] = acc;
        }
        __syncthreads();
        if (tid < 32) {
            float v = 0.f;
            if (tid < 30) {
                #pragma unroll
                for (int rg = 0; rg < 20; ++rg) v += part[rg * 32 + tid];
            }
            abuf[(b * NPEER + s) * 32 + tid] = v;
        }
    }
    // final output o_{T-1}
    gbar(ctr, 8 * (2 + 2 * T));
    if (s == 0 && tid < DOUT) {
        float v = foNo[tid];
        for (int p = 0; p < NPEER; ++p) v += obuf[(b * NPEER + p) * DOUT + tid];
        out[((size_t)(T - 1) * BB + b) * DOUT + tid] = v;
    }
}

extern "C" void kernel_launch(void* const* d_in, const int* in_sizes, int n_in,
                              void* d_out, int out_size, void* d_ws, size_t ws_size,
                              hipStream_t stream) {
    const int*   sentence = (const int*)d_in[0];
    const int*   speaker  = (const int*)d_in[1];
    const float* LutP = (const float*)d_in[2];
    const float* LutS = (const float*)d_in[3];
    const float* NaW  = (const float*)d_in[4];
    const float* NaB  = (const float*)d_in[5];
    const float* NuW  = (const float*)d_in[6];
    const float* NuB  = (const float*)d_in[7];
    const float* NoW  = (const float*)d_in[8];
    const float* NoB  = (const float*)d_in[9];
    const float* FuW  = (const float*)d_in[10];
    const float* FuB  = (const float*)d_in[11];
    const float* FoW  = (const float*)d_in[12];
    const float* FoB  = (const float*)d_in[13];
    const int*   Tptr = (const int*)d_in[14];
    float* ws   = (float*)d_ws;
    float* outp = (float*)d_out;

    hipLaunchKernelGGL(prep_kernel, dim3(1), dim3(1024), 0, stream, (int*)d_ws);
    hipLaunchKernelGGL(recur_kernel, dim3(BB * NPEER), dim3(NTH), 0, stream,
                       sentence, speaker, LutP, LutS, NaW, NaB,
                       NuW, NuB, NoW, NoB, FuW, FuB, FoW, FoB,
                       ws, Tptr, outp);
}